// Round 1
// baseline (1191.272 us; speedup 1.0000x reference)
//
#include <hip/hip_runtime.h>

// SegDecoder: 3-layer cross-attention decoder on MI355X (gfx950).
// B=16, Nq=64, Nk=4096, C=512, H=8, hd=64, FF=2048, L=3.
// All GEMMs via bf16 MFMA (v_mfma_f32_16x16x32_bf16), fp32 accumulate.

typedef unsigned short u16;
typedef __attribute__((ext_vector_type(8))) short short8;
typedef __attribute__((ext_vector_type(4))) float f32x4;

__device__ __forceinline__ float b2f(u16 u) {
    union { unsigned int i; float f; } v; v.i = ((unsigned int)u) << 16; return v.f;
}
__device__ __forceinline__ u16 f2b(float f) {  // round-to-nearest-even
    unsigned int x = __float_as_uint(f);
    x += 0x7fffu + ((x >> 16) & 1u);
    return (u16)(x >> 16);
}

__device__ __forceinline__ float waveSum(float v) {
#pragma unroll
    for (int o = 32; o > 0; o >>= 1) v += __shfl_xor(v, o);
    return v;
}
__device__ __forceinline__ float waveMax(float v) {
#pragma unroll
    for (int o = 32; o > 0; o >>= 1) v = fmaxf(v, __shfl_xor(v, o));
    return v;
}

// ---------------------------------------------------------------------------
// Generic batched GEMM:  C = alpha * A(M,K) @ Bt(N,K)^T [+ bias]
// A, Bt bf16 row-major with runtime ld; C fp32 or bf16.
// Batch z decomposed as zq=z/bdiv, zr=z%bdiv; offsets zq*s?1 + zr*s?2 (elems).
// Tiles: TM x TN, BK=32, 4 waves in 2x2, each wave TM/2 x TN/2.
// ---------------------------------------------------------------------------
template<int TM, int TN, bool OUT_BF16, bool RELU, bool BIAS_ROW, bool HAS_BIAS>
__global__ __launch_bounds__(256) void gemm_bt_k(
    const u16* __restrict__ A, const u16* __restrict__ Bt,
    const float* __restrict__ bias, void* __restrict__ Cout,
    int K, int lda, int ldb, int ldc,
    int bdiv, long sA1, long sA2, long sB1, long sB2, long sC1, long sC2,
    float alpha)
{
    __shared__ u16 As[TM][32];
    __shared__ u16 Bs[TN][32];
    const int t = threadIdx.x;
    const int lane = t & 63;
    const int z = blockIdx.z;
    const int zq = z / bdiv, zr = z % bdiv;
    A  += (long)zq * sA1 + (long)zr * sA2;
    Bt += (long)zq * sB1 + (long)zr * sB2;
    const long cbase = (long)zq * sC1 + (long)zr * sC2;
    const int n0 = blockIdx.x * TN;
    const int m0 = blockIdx.y * TM;
    constexpr int FM = TM / 32, FN = TN / 32;
    const int wave = t >> 6;
    const int wr = wave >> 1, wc = wave & 1;

    f32x4 acc[FM][FN];
#pragma unroll
    for (int i = 0; i < FM; ++i)
#pragma unroll
        for (int j = 0; j < FN; ++j) acc[i][j] = (f32x4){0.f, 0.f, 0.f, 0.f};

    const int srow = t >> 2;          // 64 rows per staging round
    const int scol = (t & 3) * 8;     // 8 bf16 = 16B per thread

    for (int k0 = 0; k0 < K; k0 += 32) {
        __syncthreads();
#pragma unroll
        for (int r = 0; r < TM / 64; ++r) {
            const int row = r * 64 + srow;
            *(short8*)(&As[row][scol]) =
                *(const short8*)(A + (long)(m0 + row) * lda + k0 + scol);
        }
#pragma unroll
        for (int r = 0; r < TN / 64; ++r) {
            const int row = r * 64 + srow;
            *(short8*)(&Bs[row][scol]) =
                *(const short8*)(Bt + (long)(n0 + row) * ldb + k0 + scol);
        }
        __syncthreads();
        const int kk = (lane >> 4) * 8;
        const int rl = lane & 15;
        short8 af[FM], bf[FN];
#pragma unroll
        for (int i = 0; i < FM; ++i)
            af[i] = *(const short8*)(&As[wr * (TM / 2) + i * 16 + rl][kk]);
#pragma unroll
        for (int j = 0; j < FN; ++j)
            bf[j] = *(const short8*)(&Bs[wc * (TN / 2) + j * 16 + rl][kk]);
#pragma unroll
        for (int i = 0; i < FM; ++i)
#pragma unroll
            for (int j = 0; j < FN; ++j)
                acc[i][j] = __builtin_amdgcn_mfma_f32_16x16x32_bf16(
                    af[i], bf[j], acc[i][j], 0, 0, 0);
    }

    const int r0 = (lane >> 4) * 4;
    const int c0 = lane & 15;
#pragma unroll
    for (int i = 0; i < FM; ++i) {
#pragma unroll
        for (int j = 0; j < FN; ++j) {
#pragma unroll
            for (int r = 0; r < 4; ++r) {
                const int row = m0 + wr * (TM / 2) + i * 16 + r0 + r;
                const int col = n0 + wc * (TN / 2) + j * 16 + c0;
                float v = acc[i][j][r] * alpha;
                if constexpr (HAS_BIAS) {
                    if constexpr (BIAS_ROW) v += bias[row]; else v += bias[col];
                }
                if constexpr (RELU) v = fmaxf(v, 0.f);
                const long idx = cbase + (long)row * ldc + col;
                if constexpr (OUT_BF16) ((u16*)Cout)[idx] = f2b(v);
                else                    ((float*)Cout)[idx] = v;
            }
        }
    }
}

// ---------------------------------------------------------------------------
// softmax + affinity gate + head-averaged score output.
// block = (b,q); S,P layout (B,H,64,4096) bf16; attns (B,64,4096) fp32.
// ---------------------------------------------------------------------------
__global__ __launch_bounds__(256) void softmax_gate_k(
    const u16* __restrict__ S, const float* __restrict__ aff,
    u16* __restrict__ P, float* __restrict__ attns)
{
    const int bq = blockIdx.x;
    const int b = bq >> 6, q = bq & 63;
    const int t = threadIdx.x;
    const int w = t >> 6, lane = t & 63;
    __shared__ float red[4];
    const int kb = t * 16;

    float affv[16];
#pragma unroll
    for (int j = 0; j < 16; ++j) affv[j] = aff[b * 4096 + kb + j];
    float attnacc[16];
#pragma unroll
    for (int j = 0; j < 16; ++j) attnacc[j] = 0.f;

    for (int h = 0; h < 8; ++h) {
        const long roff = (((long)(b * 8 + h)) * 64 + q) * 4096;
        const u16* Srow = S + roff;
        float v[16];
        short8 s0 = *(const short8*)(Srow + kb);
        short8 s1 = *(const short8*)(Srow + kb + 8);
#pragma unroll
        for (int j = 0; j < 8; ++j) { v[j] = b2f((u16)s0[j]); v[8 + j] = b2f((u16)s1[j]); }

        float m = -3.0e38f;
#pragma unroll
        for (int j = 0; j < 16; ++j) m = fmaxf(m, v[j]);
        m = waveMax(m);
        __syncthreads();
        if (lane == 0) red[w] = m;
        __syncthreads();
        m = fmaxf(fmaxf(red[0], red[1]), fmaxf(red[2], red[3]));

        float e[16]; float s = 0.f;
#pragma unroll
        for (int j = 0; j < 16; ++j) { e[j] = __expf(v[j] - m); s += e[j]; }
        s = waveSum(s);
        __syncthreads();
        if (lane == 0) red[w] = s;
        __syncthreads();
        s = red[0] + red[1] + red[2] + red[3];
        const float inv = 1.f / s;

        u16* Prow = P + roff;
        short8 p0, p1;
#pragma unroll
        for (int j = 0; j < 8; ++j) {
            p0[j] = (short)f2b(affv[j]     * e[j]     * inv);
            p1[j] = (short)f2b(affv[8 + j] * e[8 + j] * inv);
        }
        *(short8*)(Prow + kb)     = p0;
        *(short8*)(Prow + kb + 8) = p1;
#pragma unroll
        for (int j = 0; j < 16; ++j) attnacc[j] += v[j];
    }
    float* arow = attns + (long)bq * 4096;
#pragma unroll
    for (int j = 0; j < 16; ++j) arow[kb + j] = attnacc[j] * 0.125f;  // /H
}

// ---------------------------------------------------------------------------
// aff[b,k] = sigmoid(SCALE/H * dot(extra[b,:], K[b,k,:])); one wave per (b,k).
// ---------------------------------------------------------------------------
__global__ __launch_bounds__(256) void aff_k(
    const u16* __restrict__ K16, const float* __restrict__ extra,
    float* __restrict__ affb, float* __restrict__ affs_out)
{
    const int gw = blockIdx.x * 4 + (threadIdx.x >> 6);
    const int lane = threadIdx.x & 63;
    const int b = gw >> 12, k = gw & 4095;
    const u16* kr = K16 + ((long)(b * 4096 + k)) * 512 + lane * 8;
    const float* ex = extra + b * 512 + lane * 8;
    short8 kv = *(const short8*)kr;
    float s = 0.f;
#pragma unroll
    for (int j = 0; j < 8; ++j) s += ex[j] * b2f((u16)kv[j]);
    s = waveSum(s);
    if (lane == 0) {
        float a = 1.f / (1.f + __expf(-0.015625f * s));  // SCALE/H = 0.125/8
        affb[b * 4096 + k] = a;
        affs_out[b * 4096 + k] = a;
    }
}

// ---------------------------------------------------------------------------
// x = LN(x + add; g, beta); updates x (fp32) and x16 (bf16); optional out copy.
// block = row (512 cols, 256 threads x 2).
// ---------------------------------------------------------------------------
template<bool WRITE_OUT>
__global__ __launch_bounds__(256) void ln_k(
    float* __restrict__ x, const float* __restrict__ add,
    const float* __restrict__ g, const float* __restrict__ be,
    u16* __restrict__ x16, float* __restrict__ outp)
{
    const int r = blockIdx.x, t = threadIdx.x;
    const int w = t >> 6, lane = t & 63;
    __shared__ float red[4];
    float* xr = x + (long)r * 512;
    const float* ar = add + (long)r * 512;
    const float v0 = xr[2 * t]     + ar[2 * t];
    const float v1 = xr[2 * t + 1] + ar[2 * t + 1];
    float s = waveSum(v0 + v1);
    if (lane == 0) red[w] = s;
    __syncthreads();
    s = red[0] + red[1] + red[2] + red[3];
    const float mu = s * (1.f / 512.f);
    const float d0 = v0 - mu, d1 = v1 - mu;
    __syncthreads();
    float vs = waveSum(d0 * d0 + d1 * d1);
    if (lane == 0) red[w] = vs;
    __syncthreads();
    vs = red[0] + red[1] + red[2] + red[3];
    const float rs = rsqrtf(vs * (1.f / 512.f) + 1e-5f);
    const float o0 = g[2 * t]     * d0 * rs + be[2 * t];
    const float o1 = g[2 * t + 1] * d1 * rs + be[2 * t + 1];
    xr[2 * t] = o0; xr[2 * t + 1] = o1;
    x16[(long)r * 512 + 2 * t]     = f2b(o0);
    x16[(long)r * 512 + 2 * t + 1] = f2b(o1);
    if constexpr (WRITE_OUT) {
        outp[(long)r * 512 + 2 * t]     = o0;
        outp[(long)r * 512 + 2 * t + 1] = o1;
    }
}

// fp32 -> bf16 bulk convert (8 per thread)
__global__ __launch_bounds__(256) void cvt16_k(
    const float* __restrict__ src, u16* __restrict__ dst, long n)
{
    const long i = ((long)blockIdx.x * 256 + threadIdx.x) * 8;
    if (i >= n) return;
    const float4 a = *(const float4*)(src + i);
    const float4 b = *(const float4*)(src + i + 4);
    short8 r;
    r[0] = (short)f2b(a.x); r[1] = (short)f2b(a.y); r[2] = (short)f2b(a.z); r[3] = (short)f2b(a.w);
    r[4] = (short)f2b(b.x); r[5] = (short)f2b(b.y); r[6] = (short)f2b(b.z); r[7] = (short)f2b(b.w);
    *(short8*)(dst + i) = r;
}

// x = copy(queries) fp32 + bf16
__global__ __launch_bounds__(256) void initx_k(
    const float* __restrict__ src, float* __restrict__ x, u16* __restrict__ x16)
{
    const long i = ((long)blockIdx.x * 256 + threadIdx.x) * 8;
    const float4 a = *(const float4*)(src + i);
    const float4 b = *(const float4*)(src + i + 4);
    *(float4*)(x + i) = a;
    *(float4*)(x + i + 4) = b;
    short8 r;
    r[0] = (short)f2b(a.x); r[1] = (short)f2b(a.y); r[2] = (short)f2b(a.z); r[3] = (short)f2b(a.w);
    r[4] = (short)f2b(b.x); r[5] = (short)f2b(b.y); r[6] = (short)f2b(b.z); r[7] = (short)f2b(b.w);
    *(short8*)(x16 + i) = r;
}

// W (K,N) fp32 -> WT (N,K) bf16, batched over blockIdx.z
__global__ __launch_bounds__(256) void transpose_w_k(
    const float* __restrict__ W, u16* __restrict__ WT, int K, int N)
{
    __shared__ float tile[32][33];
    const int z = blockIdx.z;
    W  += (size_t)z * K * N;
    WT += (size_t)z * K * N;
    const int n0 = blockIdx.x * 32, k0 = blockIdx.y * 32;
    const int tx = threadIdx.x & 31, ty = threadIdx.x >> 5;
#pragma unroll
    for (int j = 0; j < 32; j += 8)
        tile[ty + j][tx] = W[(size_t)(k0 + ty + j) * N + n0 + tx];
    __syncthreads();
#pragma unroll
    for (int j = 0; j < 32; j += 8)
        WT[(size_t)(n0 + ty + j) * K + k0 + tx] = f2b(tile[tx][ty + j]);
}

// ---------------------------------------------------------------------------
extern "C" void kernel_launch(void* const* d_in, const int* in_sizes, int n_in,
                              void* d_out, int out_size, void* d_ws, size_t ws_size,
                              hipStream_t stream)
{
    (void)in_sizes; (void)n_in; (void)out_size; (void)ws_size;
    const float* queries = (const float*)d_in[0];
    const float* feat    = (const float*)d_in[1];
    const float* extra   = (const float*)d_in[2];
    const float* Wq = (const float*)d_in[3];  const float* bq = (const float*)d_in[4];
    const float* Wk = (const float*)d_in[5];  const float* bk = (const float*)d_in[6];
    const float* Wv = (const float*)d_in[7];  const float* bv = (const float*)d_in[8];
    const float* Wo = (const float*)d_in[9];  const float* bo = (const float*)d_in[10];
    const float* W1 = (const float*)d_in[11]; const float* b1 = (const float*)d_in[12];
    const float* W2 = (const float*)d_in[13]; const float* b2 = (const float*)d_in[14];
    const float* g2 = (const float*)d_in[15]; const float* be2 = (const float*)d_in[16];
    const float* g3 = (const float*)d_in[17]; const float* be3 = (const float*)d_in[18];

    char* wsb = (char*)d_ws;
    size_t off = 0;
    auto alloc = [&](size_t bytes) -> char* {
        char* p = wsb + off; off += (bytes + 255) & ~(size_t)255; return p;
    };
    u16*  feat16 = (u16*)alloc(33554432ull * 2);   // (B*Nk, C) bf16
    u16*  WqT = (u16*)alloc(786432ull * 2);        // (L,512,512) transposed
    u16*  WkT = (u16*)alloc(786432ull * 2);
    u16*  WvT = (u16*)alloc(786432ull * 2);
    u16*  WoT = (u16*)alloc(786432ull * 2);
    u16*  W1T = (u16*)alloc(3145728ull * 2);       // (L,2048,512)
    u16*  W2T = (u16*)alloc(3145728ull * 2);       // (L,512,2048)
    u16*  K16 = (u16*)alloc(33554432ull * 2);      // (B,Nk,C); later reused as P (B,H,64,4096)
    u16*  VT16 = (u16*)alloc(33554432ull * 2);     // (B,C,Nk)
    u16*  q16 = (u16*)alloc(524288ull * 2);        // (B*Nq, C)
    u16*  S16 = (u16*)alloc(33554432ull * 2);      // (B,H,64,4096) scores*SCALE
    float* affb  = (float*)alloc(65536ull * 4);    // (B,Nk)
    u16*  o16 = (u16*)alloc(524288ull * 2);        // attention out (B,Nq,C)
    float* oproj = (float*)alloc(524288ull * 4);
    float* xb    = (float*)alloc(524288ull * 4);
    u16*  x16 = (u16*)alloc(524288ull * 2);
    u16*  h116 = (u16*)alloc(2097152ull * 2);      // (B*Nq, 2048)
    float* ffb   = (float*)alloc(524288ull * 4);
    u16*  P16 = K16;                               // alias: K dead after S-GEMM/aff

    float* out_f = (float*)d_out;
    float* outs_base  = out_f;                     // (3,16,64,512)
    float* attns_base = out_f + 1572864;           // (3,16,64,4096)
    float* affs_base  = out_f + 14155776;          // (3,16,1,1,4096)

    // prep
    cvt16_k<<<16384, 256, 0, stream>>>(feat, feat16, 33554432L);
    initx_k<<<256, 256, 0, stream>>>(queries, xb, x16);
    transpose_w_k<<<dim3(16, 16, 3), 256, 0, stream>>>(Wq, WqT, 512, 512);
    transpose_w_k<<<dim3(16, 16, 3), 256, 0, stream>>>(Wk, WkT, 512, 512);
    transpose_w_k<<<dim3(16, 16, 3), 256, 0, stream>>>(Wv, WvT, 512, 512);
    transpose_w_k<<<dim3(16, 16, 3), 256, 0, stream>>>(Wo, WoT, 512, 512);
    transpose_w_k<<<dim3(64, 16, 3), 256, 0, stream>>>(W1, W1T, 512, 2048);
    transpose_w_k<<<dim3(16, 64, 3), 256, 0, stream>>>(W2, W2T, 2048, 512);

    for (int i = 0; i < 3; ++i) {
        // K = feat @ Wk + bk   (M=65536, N=512, K=512) -> bf16 (B,Nk,C)
        gemm_bt_k<128, 128, true, false, false, true><<<dim3(4, 512, 1), 256, 0, stream>>>(
            feat16, WkT + i * 262144, bk + i * 512, K16,
            512, 512, 512, 512, 1, 0, 0, 0, 0, 0, 0, 1.f);
        // VT[b] = (feat[b] @ Wv)^T + bv  as  WvT(512,512) @ feat[b]^T  -> (B,C,Nk)
        gemm_bt_k<128, 128, true, false, true, true><<<dim3(32, 4, 16), 256, 0, stream>>>(
            WvT + i * 262144, feat16, bv + i * 512, VT16,
            512, 512, 512, 4096, 1, 0, 0, 2097152, 0, 2097152, 0, 1.f);
        // q = x @ Wq + bq  (1024 x 512)
        gemm_bt_k<128, 128, true, false, false, true><<<dim3(4, 8, 1), 256, 0, stream>>>(
            x16, WqT + i * 262144, bq + i * 512, q16,
            512, 512, 512, 512, 1, 0, 0, 0, 0, 0, 0, 1.f);
        // affinity gate
        aff_k<<<16384, 256, 0, stream>>>(K16, extra, affb, affs_base + i * 65536);
        // S[b,h] = SCALE * q_h @ K_h^T   (batch 128: M=64,N=4096,K=64)
        gemm_bt_k<64, 128, true, false, false, false><<<dim3(32, 1, 128), 256, 0, stream>>>(
            q16, K16, nullptr, S16,
            64, 512, 512, 4096, 8, 32768, 64, 2097152, 64, 2097152, 262144, 0.125f);
        // softmax + gate -> P (reuses K16), head-avg scores -> attns
        softmax_gate_k<<<1024, 256, 0, stream>>>(
            S16, affb, P16, attns_base + (size_t)i * 4194304);
        // o[b,h] = P @ V  via VT  (batch 128: M=64,N=64,K=4096) -> (B,Nq,C) bf16
        gemm_bt_k<64, 64, true, false, false, false><<<dim3(1, 1, 128), 256, 0, stream>>>(
            P16, VT16, nullptr, o16,
            4096, 4096, 4096, 512, 8, 2097152, 262144, 2097152, 262144, 32768, 64, 1.f);
        // o @ Wo + bo -> fp32
        gemm_bt_k<128, 128, false, false, false, true><<<dim3(4, 8, 1), 256, 0, stream>>>(
            o16, WoT + i * 262144, bo + i * 512, oproj,
            512, 512, 512, 512, 1, 0, 0, 0, 0, 0, 0, 1.f);
        // x = LN(x + oproj; g2, beta2)
        ln_k<false><<<1024, 256, 0, stream>>>(xb, oproj, g2 + i * 512, be2 + i * 512, x16, nullptr);
        // h1 = relu(x @ W1 + b1) -> bf16 (1024 x 2048)
        gemm_bt_k<128, 128, true, true, false, true><<<dim3(16, 8, 1), 256, 0, stream>>>(
            x16, W1T + (size_t)i * 1048576, b1 + i * 2048, h116,
            512, 512, 512, 2048, 1, 0, 0, 0, 0, 0, 0, 1.f);
        // ff = h1 @ W2 + b2 -> fp32
        gemm_bt_k<128, 128, false, false, false, true><<<dim3(4, 8, 1), 256, 0, stream>>>(
            h116, W2T + (size_t)i * 1048576, b2 + i * 512, ffb,
            2048, 2048, 2048, 512, 1, 0, 0, 0, 0, 0, 0, 1.f);
        // x = LN(x + ff; g3, beta3), write outs[i]
        ln_k<true><<<1024, 256, 0, stream>>>(xb, ffb, g3 + i * 512, be3 + i * 512, x16,
                                             outs_base + (size_t)i * 524288);
    }
}

// Round 2
// 1033.530 us; speedup vs baseline: 1.1526x; 1.1526x over previous
//
#include <hip/hip_runtime.h>

// SegDecoder: 3-layer cross-attention decoder on MI355X (gfx950).
// B=16, Nq=64, Nk=4096, C=512, H=8, hd=64, FF=2048, L=3.
// All GEMMs via bf16 MFMA (v_mfma_f32_16x16x32_bf16), fp32 accumulate.
// R2: global_load_lds(16B) staging + XOR bank swizzle; split-K PV; aff fused
// into feat convert.

typedef unsigned short u16;
typedef __attribute__((ext_vector_type(8))) short short8;
typedef __attribute__((ext_vector_type(4))) short short4v;
typedef __attribute__((ext_vector_type(4))) float f32x4;

__device__ __forceinline__ float b2f(u16 u) {
    union { unsigned int i; float f; } v; v.i = ((unsigned int)u) << 16; return v.f;
}
__device__ __forceinline__ u16 f2b(float f) {  // round-to-nearest-even
    unsigned int x = __float_as_uint(f);
    x += 0x7fffu + ((x >> 16) & 1u);
    return (u16)(x >> 16);
}

__device__ __forceinline__ float waveSum(float v) {
#pragma unroll
    for (int o = 32; o > 0; o >>= 1) v += __shfl_xor(v, o);
    return v;
}
__device__ __forceinline__ float waveMax(float v) {
#pragma unroll
    for (int o = 32; o > 0; o >>= 1) v = fmaxf(v, __shfl_xor(v, o));
    return v;
}

// async global->LDS, 16B per lane. LDS dest is wave-uniform base + lane*16.
__device__ __forceinline__ void gl_lds16(const void* g, void* l) {
    __builtin_amdgcn_global_load_lds(
        (__attribute__((address_space(1))) void*)g,
        (__attribute__((address_space(3))) void*)l, 16, 0, 0);
}

// ---------------------------------------------------------------------------
// Generic batched GEMM:  C = alpha * A(M,K) @ Bt(N,K)^T [+ bias]
// A, Bt bf16 row-major with runtime ld; C fp32 or bf16.
// Batch z: zq=z/bdiv, zr=z%bdiv; offsets zq*s?1 + zr*s?2 (elems).
// Tiles: TM x TN (multiples of 64), BK=32, 4 waves in 2x2.
// LDS tile rows of 32 bf16 (64B). 16B units XOR-swizzled: u_phys =
// u_log ^ ((row>>1)&3). Staged via global_load_lds with pre-swizzled global
// source (linear LDS dest), read back with swizzled ds_read_b128.
// ---------------------------------------------------------------------------
template<int TM, int TN, bool OUT_BF16, bool RELU, bool BIAS_ROW, bool HAS_BIAS>
__global__ __launch_bounds__(256) void gemm_bt_k(
    const u16* __restrict__ A, const u16* __restrict__ Bt,
    const float* __restrict__ bias, void* __restrict__ Cout,
    int K, int lda, int ldb, int ldc,
    int bdiv, long sA1, long sA2, long sB1, long sB2, long sC1, long sC2,
    float alpha)
{
    __shared__ u16 As[TM][32];
    __shared__ u16 Bs[TN][32];
    const int t = threadIdx.x;
    const int lane = t & 63;
    const int wave = t >> 6;
    const int z = blockIdx.z;
    const int zq = z / bdiv, zr = z % bdiv;
    A  += (long)zq * sA1 + (long)zr * sA2;
    Bt += (long)zq * sB1 + (long)zr * sB2;
    const long cbase = (long)zq * sC1 + (long)zr * sC2;
    const int n0 = blockIdx.x * TN;
    const int m0 = blockIdx.y * TM;
    constexpr int FM = TM / 32, FN = TN / 32;
    const int wr = wave >> 1, wc = wave & 1;

    f32x4 acc[FM][FN];
#pragma unroll
    for (int i = 0; i < FM; ++i)
#pragma unroll
        for (int j = 0; j < FN; ++j) acc[i][j] = (f32x4){0.f, 0.f, 0.f, 0.f};

    // staging geometry: one issue = 16 rows x 64B = 1KB (64 lanes x 16B)
    const int srow = lane >> 2;   // row within issue
    const int up   = lane & 3;    // physical 16B unit within row

    for (int k0 = 0; k0 < K; k0 += 32) {
        __syncthreads();
#pragma unroll
        for (int r = 0; r < TM / 64; ++r) {
            const int br = (wave * (TM / 64) + r) * 16;
            const int row = br + srow;
            const int ul = up ^ ((row >> 1) & 3);   // logical unit to fetch
            gl_lds16(A + (long)(m0 + row) * lda + k0 + ul * 8, &As[br][0]);
        }
#pragma unroll
        for (int r = 0; r < TN / 64; ++r) {
            const int br = (wave * (TN / 64) + r) * 16;
            const int row = br + srow;
            const int ul = up ^ ((row >> 1) & 3);
            gl_lds16(Bt + (long)(n0 + row) * ldb + k0 + ul * 8, &Bs[br][0]);
        }
        __syncthreads();   // drains vmcnt (global_load_lds) + lgkmcnt

        const int uread = lane >> 4;   // logical 16B unit = MFMA k-slot
        const int rl = lane & 15;
        short8 af[FM], bf[FN];
#pragma unroll
        for (int i = 0; i < FM; ++i) {
            const int R = wr * (TM / 2) + i * 16 + rl;
            af[i] = *(const short8*)(&As[R][(uread ^ ((R >> 1) & 3)) * 8]);
        }
#pragma unroll
        for (int j = 0; j < FN; ++j) {
            const int R = wc * (TN / 2) + j * 16 + rl;
            bf[j] = *(const short8*)(&Bs[R][(uread ^ ((R >> 1) & 3)) * 8]);
        }
#pragma unroll
        for (int i = 0; i < FM; ++i)
#pragma unroll
            for (int j = 0; j < FN; ++j)
                acc[i][j] = __builtin_amdgcn_mfma_f32_16x16x32_bf16(
                    af[i], bf[j], acc[i][j], 0, 0, 0);
    }

    const int r0 = (lane >> 4) * 4;
    const int c0 = lane & 15;
#pragma unroll
    for (int i = 0; i < FM; ++i) {
#pragma unroll
        for (int j = 0; j < FN; ++j) {
#pragma unroll
            for (int r = 0; r < 4; ++r) {
                const int row = m0 + wr * (TM / 2) + i * 16 + r0 + r;
                const int col = n0 + wc * (TN / 2) + j * 16 + c0;
                float v = acc[i][j][r] * alpha;
                if constexpr (HAS_BIAS) {
                    if constexpr (BIAS_ROW) v += bias[row]; else v += bias[col];
                }
                if constexpr (RELU) v = fmaxf(v, 0.f);
                const long idx = cbase + (long)row * ldc + col;
                if constexpr (OUT_BF16) ((u16*)Cout)[idx] = f2b(v);
                else                    ((float*)Cout)[idx] = v;
            }
        }
    }
}

// ---------------------------------------------------------------------------
// split-K PV reduce: part (8,128,64,64) fp32 -> o16 (16,64,512) bf16
// ---------------------------------------------------------------------------
__global__ __launch_bounds__(256) void pv_reduce_k(
    const float* __restrict__ part, u16* __restrict__ o16)
{
    const int i = blockIdx.x * 256 + threadIdx.x;   // 131072 threads x 4 elems
    const int d4 = i & 15;
    const int q  = (i >> 4) & 63;
    const int bh = i >> 10;                          // 0..127
    const float* p = part + (long)bh * 4096 + q * 64 + d4 * 4;
    float4 s = {0.f, 0.f, 0.f, 0.f};
#pragma unroll
    for (int sp = 0; sp < 8; ++sp) {
        const float4 v = *(const float4*)(p + (long)sp * 524288);
        s.x += v.x; s.y += v.y; s.z += v.z; s.w += v.w;
    }
    const int b = bh >> 3, h = bh & 7;
    u16* o = o16 + (long)b * 32768 + q * 512 + h * 64 + d4 * 4;
    short4v r;
    r[0] = (short)f2b(s.x); r[1] = (short)f2b(s.y);
    r[2] = (short)f2b(s.z); r[3] = (short)f2b(s.w);
    *(short4v*)o = r;
}

// ---------------------------------------------------------------------------
// softmax + affinity gate + head-averaged score output.
// block = (b,q); S,P layout (B,H,64,4096) bf16; attns (B,64,4096) fp32.
// ---------------------------------------------------------------------------
__global__ __launch_bounds__(256) void softmax_gate_k(
    const u16* __restrict__ S, const float* __restrict__ aff,
    u16* __restrict__ P, float* __restrict__ attns)
{
    const int bq = blockIdx.x;
    const int b = bq >> 6, q = bq & 63;
    const int t = threadIdx.x;
    const int w = t >> 6, lane = t & 63;
    __shared__ float red[4];
    const int kb = t * 16;

    float affv[16];
#pragma unroll
    for (int j = 0; j < 16; ++j) affv[j] = aff[b * 4096 + kb + j];
    float attnacc[16];
#pragma unroll
    for (int j = 0; j < 16; ++j) attnacc[j] = 0.f;

    for (int h = 0; h < 8; ++h) {
        const long roff = (((long)(b * 8 + h)) * 64 + q) * 4096;
        const u16* Srow = S + roff;
        float v[16];
        short8 s0 = *(const short8*)(Srow + kb);
        short8 s1 = *(const short8*)(Srow + kb + 8);
#pragma unroll
        for (int j = 0; j < 8; ++j) { v[j] = b2f((u16)s0[j]); v[8 + j] = b2f((u16)s1[j]); }

        float m = -3.0e38f;
#pragma unroll
        for (int j = 0; j < 16; ++j) m = fmaxf(m, v[j]);
        m = waveMax(m);
        __syncthreads();
        if (lane == 0) red[w] = m;
        __syncthreads();
        m = fmaxf(fmaxf(red[0], red[1]), fmaxf(red[2], red[3]));

        float e[16]; float s = 0.f;
#pragma unroll
        for (int j = 0; j < 16; ++j) { e[j] = __expf(v[j] - m); s += e[j]; }
        s = waveSum(s);
        __syncthreads();
        if (lane == 0) red[w] = s;
        __syncthreads();
        s = red[0] + red[1] + red[2] + red[3];
        const float inv = 1.f / s;

        u16* Prow = P + roff;
        short8 p0, p1;
#pragma unroll
        for (int j = 0; j < 8; ++j) {
            p0[j] = (short)f2b(affv[j]     * e[j]     * inv);
            p1[j] = (short)f2b(affv[8 + j] * e[8 + j] * inv);
        }
        *(short8*)(Prow + kb)     = p0;
        *(short8*)(Prow + kb + 8) = p1;
#pragma unroll
        for (int j = 0; j < 16; ++j) attnacc[j] += v[j];
    }
    float* arow = attns + (long)bq * 4096;
#pragma unroll
    for (int j = 0; j < 16; ++j) arow[kb + j] = attnacc[j] * 0.125f;  // /H
}

// ---------------------------------------------------------------------------
// u[l][b][c'] = sum_c Wk[l][c'][c] * extra[b][c]   (for the aff gate)
// grid (3, 128), block 256: wave = one c' row, 16 b accumulated per wave.
// ---------------------------------------------------------------------------
__global__ __launch_bounds__(256) void umat_k(
    const float* __restrict__ Wk, const float* __restrict__ extra,
    float* __restrict__ u)
{
    __shared__ float ex[16][512];
    const int l = blockIdx.x;
    const int t = threadIdx.x;
    for (int i = t; i < 16 * 512 / 4; i += 256)
        ((float4*)&ex[0][0])[i] = ((const float4*)extra)[i];
    __syncthreads();
    const int lane = t & 63, wave = t >> 6;
    const int row = blockIdx.y * 4 + wave;          // c' in [0,512)
    const float* wrow = Wk + ((size_t)l * 512 + row) * 512 + lane * 8;
    float w[8];
#pragma unroll
    for (int j = 0; j < 8; ++j) w[j] = wrow[j];
    float s[16];
#pragma unroll
    for (int b = 0; b < 16; ++b) {
        float x = 0.f;
#pragma unroll
        for (int j = 0; j < 8; ++j) x += w[j] * ex[b][lane * 8 + j];
        s[b] = waveSum(x);
    }
    if (lane < 16) u[((size_t)l * 16 + lane) * 512 + row] = s[lane];
}

// cb[l*16+b] = dot(extra[b], bk[l])
__global__ __launch_bounds__(256) void cbk_k(
    const float* __restrict__ bk, const float* __restrict__ extra,
    float* __restrict__ cb)
{
    const int gw = blockIdx.x * 4 + (threadIdx.x >> 6);  // 48 waves
    const int lane = threadIdx.x & 63;
    const int l = gw >> 4, b = gw & 15;
    float s = 0.f;
#pragma unroll
    for (int j = 0; j < 8; ++j)
        s += extra[b * 512 + lane * 8 + j] * bk[l * 512 + lane * 8 + j];
    s = waveSum(s);
    if (lane == 0) cb[gw] = s;
}

// ---------------------------------------------------------------------------
// feat fp32 -> bf16, fused with aff for all 3 layers:
// aff[l][b][k] = sigmoid(SCALE/H * (feat[b,k,:]·u[l][b] + cb[l][b]))
// one wave per feat row (65536 rows).
// ---------------------------------------------------------------------------
__global__ __launch_bounds__(256) void cvt16_aff_k(
    const float* __restrict__ feat, u16* __restrict__ dst,
    const float* __restrict__ u, const float* __restrict__ cb,
    float* __restrict__ affb, float* __restrict__ affs_out)
{
    const int t = blockIdx.x * 256 + threadIdx.x;
    const long i = (long)t * 8;
    const int lane = threadIdx.x & 63;
    const int r = t >> 6;           // row (b*4096 + k)
    const int b = r >> 12;
    const float4 a0 = *(const float4*)(feat + i);
    const float4 a1 = *(const float4*)(feat + i + 4);
    short8 o;
    o[0] = (short)f2b(a0.x); o[1] = (short)f2b(a0.y);
    o[2] = (short)f2b(a0.z); o[3] = (short)f2b(a0.w);
    o[4] = (short)f2b(a1.x); o[5] = (short)f2b(a1.y);
    o[6] = (short)f2b(a1.z); o[7] = (short)f2b(a1.w);
    *(short8*)(dst + i) = o;
    const float f[8] = {a0.x, a0.y, a0.z, a0.w, a1.x, a1.y, a1.z, a1.w};
#pragma unroll
    for (int l = 0; l < 3; ++l) {
        const float* ur = u + ((size_t)l * 16 + b) * 512 + lane * 8;
        float s = 0.f;
#pragma unroll
        for (int j = 0; j < 8; ++j) s += f[j] * ur[j];
        s = waveSum(s);
        if (lane == 0) {
            const float av = 1.f / (1.f + __expf(-0.015625f * (s + cb[l * 16 + b])));
            affb[l * 65536 + r] = av;
            affs_out[l * 65536 + r] = av;
        }
    }
}

// ---------------------------------------------------------------------------
// x = LN(x + add; g, beta); updates x (fp32) and x16 (bf16); optional out copy.
// ---------------------------------------------------------------------------
template<bool WRITE_OUT>
__global__ __launch_bounds__(256) void ln_k(
    float* __restrict__ x, const float* __restrict__ add,
    const float* __restrict__ g, const float* __restrict__ be,
    u16* __restrict__ x16, float* __restrict__ outp)
{
    const int r = blockIdx.x, t = threadIdx.x;
    const int w = t >> 6, lane = t & 63;
    __shared__ float red[4];
    float* xr = x + (long)r * 512;
    const float* ar = add + (long)r * 512;
    const float v0 = xr[2 * t]     + ar[2 * t];
    const float v1 = xr[2 * t + 1] + ar[2 * t + 1];
    float s = waveSum(v0 + v1);
    if (lane == 0) red[w] = s;
    __syncthreads();
    s = red[0] + red[1] + red[2] + red[3];
    const float mu = s * (1.f / 512.f);
    const float d0 = v0 - mu, d1 = v1 - mu;
    __syncthreads();
    float vs = waveSum(d0 * d0 + d1 * d1);
    if (lane == 0) red[w] = vs;
    __syncthreads();
    vs = red[0] + red[1] + red[2] + red[3];
    const float rs = rsqrtf(vs * (1.f / 512.f) + 1e-5f);
    const float o0 = g[2 * t]     * d0 * rs + be[2 * t];
    const float o1 = g[2 * t + 1] * d1 * rs + be[2 * t + 1];
    xr[2 * t] = o0; xr[2 * t + 1] = o1;
    x16[(long)r * 512 + 2 * t]     = f2b(o0);
    x16[(long)r * 512 + 2 * t + 1] = f2b(o1);
    if constexpr (WRITE_OUT) {
        outp[(long)r * 512 + 2 * t]     = o0;
        outp[(long)r * 512 + 2 * t + 1] = o1;
    }
}

// x = copy(queries) fp32 + bf16
__global__ __launch_bounds__(256) void initx_k(
    const float* __restrict__ src, float* __restrict__ x, u16* __restrict__ x16)
{
    const long i = ((long)blockIdx.x * 256 + threadIdx.x) * 8;
    const float4 a = *(const float4*)(src + i);
    const float4 b = *(const float4*)(src + i + 4);
    *(float4*)(x + i) = a;
    *(float4*)(x + i + 4) = b;
    short8 r;
    r[0] = (short)f2b(a.x); r[1] = (short)f2b(a.y); r[2] = (short)f2b(a.z); r[3] = (short)f2b(a.w);
    r[4] = (short)f2b(b.x); r[5] = (short)f2b(b.y); r[6] = (short)f2b(b.z); r[7] = (short)f2b(b.w);
    *(short8*)(x16 + i) = r;
}

// W (K,N) fp32 -> WT (N,K) bf16, batched over blockIdx.z
__global__ __launch_bounds__(256) void transpose_w_k(
    const float* __restrict__ W, u16* __restrict__ WT, int K, int N)
{
    __shared__ float tile[32][33];
    const int z = blockIdx.z;
    W  += (size_t)z * K * N;
    WT += (size_t)z * K * N;
    const int n0 = blockIdx.x * 32, k0 = blockIdx.y * 32;
    const int tx = threadIdx.x & 31, ty = threadIdx.x >> 5;
#pragma unroll
    for (int j = 0; j < 32; j += 8)
        tile[ty + j][tx] = W[(size_t)(k0 + ty + j) * N + n0 + tx];
    __syncthreads();
#pragma unroll
    for (int j = 0; j < 32; j += 8)
        WT[(size_t)(n0 + ty + j) * K + k0 + tx] = f2b(tile[tx][ty + j]);
}

// ---------------------------------------------------------------------------
extern "C" void kernel_launch(void* const* d_in, const int* in_sizes, int n_in,
                              void* d_out, int out_size, void* d_ws, size_t ws_size,
                              hipStream_t stream)
{
    (void)in_sizes; (void)n_in; (void)out_size; (void)ws_size;
    const float* queries = (const float*)d_in[0];
    const float* feat    = (const float*)d_in[1];
    const float* extra   = (const float*)d_in[2];
    const float* Wq = (const float*)d_in[3];  const float* bq = (const float*)d_in[4];
    const float* Wk = (const float*)d_in[5];  const float* bk = (const float*)d_in[6];
    const float* Wv = (const float*)d_in[7];  const float* bv = (const float*)d_in[8];
    const float* Wo = (const float*)d_in[9];  const float* bo = (const float*)d_in[10];
    const float* W1 = (const float*)d_in[11]; const float* b1 = (const float*)d_in[12];
    const float* W2 = (const float*)d_in[13]; const float* b2 = (const float*)d_in[14];
    const float* g2 = (const float*)d_in[15]; const float* be2 = (const float*)d_in[16];
    const float* g3 = (const float*)d_in[17]; const float* be3 = (const float*)d_in[18];

    char* wsb = (char*)d_ws;
    size_t off = 0;
    auto alloc = [&](size_t bytes) -> char* {
        char* p = wsb + off; off += (bytes + 255) & ~(size_t)255; return p;
    };
    u16*  feat16 = (u16*)alloc(33554432ull * 2);   // (B*Nk, C) bf16
    u16*  WqT = (u16*)alloc(786432ull * 2);        // (L,512,512) transposed
    u16*  WkT = (u16*)alloc(786432ull * 2);
    u16*  WvT = (u16*)alloc(786432ull * 2);
    u16*  WoT = (u16*)alloc(786432ull * 2);
    u16*  W1T = (u16*)alloc(3145728ull * 2);       // (L,2048,512)
    u16*  W2T = (u16*)alloc(3145728ull * 2);       // (L,512,2048)
    u16*  K16 = (u16*)alloc(33554432ull * 2);      // (B,Nk,C); later reused as P
    u16*  VT16 = (u16*)alloc(33554432ull * 2);     // (B,C,Nk)
    u16*  q16 = (u16*)alloc(524288ull * 2);        // (B*Nq, C)
    u16*  S16 = (u16*)alloc(33554432ull * 2);      // (B,H,64,4096); later PV partials
    float* affb  = (float*)alloc(196608ull * 4);   // (L,B,Nk)
    u16*  o16 = (u16*)alloc(524288ull * 2);        // attention out (B,Nq,C)
    float* oproj = (float*)alloc(524288ull * 4);
    float* xb    = (float*)alloc(524288ull * 4);
    u16*  x16 = (u16*)alloc(524288ull * 2);
    u16*  h116 = (u16*)alloc(2097152ull * 2);      // (B*Nq, 2048)
    float* ffb   = (float*)alloc(524288ull * 4);
    float* uvec  = (float*)alloc(24576ull * 4);    // (L,16,512)
    float* cb    = (float*)alloc(48ull * 4);
    u16*  P16 = K16;                               // alias: K dead after S-GEMM
    float* part = (float*)S16;                     // alias: S dead after softmax

    float* out_f = (float*)d_out;
    float* outs_base  = out_f;                     // (3,16,64,512)
    float* attns_base = out_f + 1572864;           // (3,16,64,4096)
    float* affs_base  = out_f + 14155776;          // (3,16,1,1,4096)

    // prep (layer-independent)
    umat_k<<<dim3(3, 128), 256, 0, stream>>>(Wk, extra, uvec);
    cbk_k<<<12, 256, 0, stream>>>(bk, extra, cb);
    cvt16_aff_k<<<16384, 256, 0, stream>>>(feat, feat16, uvec, cb, affb, affs_base);
    initx_k<<<256, 256, 0, stream>>>(queries, xb, x16);
    transpose_w_k<<<dim3(16, 16, 3), 256, 0, stream>>>(Wq, WqT, 512, 512);
    transpose_w_k<<<dim3(16, 16, 3), 256, 0, stream>>>(Wk, WkT, 512, 512);
    transpose_w_k<<<dim3(16, 16, 3), 256, 0, stream>>>(Wv, WvT, 512, 512);
    transpose_w_k<<<dim3(16, 16, 3), 256, 0, stream>>>(Wo, WoT, 512, 512);
    transpose_w_k<<<dim3(64, 16, 3), 256, 0, stream>>>(W1, W1T, 512, 2048);
    transpose_w_k<<<dim3(16, 64, 3), 256, 0, stream>>>(W2, W2T, 2048, 512);

    for (int i = 0; i < 3; ++i) {
        // K = feat @ Wk + bk   (M=65536, N=512, K=512) -> bf16 (B,Nk,C)
        gemm_bt_k<128, 128, true, false, false, true><<<dim3(4, 512, 1), 256, 0, stream>>>(
            feat16, WkT + i * 262144, bk + i * 512, K16,
            512, 512, 512, 512, 1, 0, 0, 0, 0, 0, 0, 1.f);
        // VT[b] = (feat[b] @ Wv)^T + bv  as  WvT @ feat[b]^T -> (B,C,Nk)
        gemm_bt_k<128, 128, true, false, true, true><<<dim3(32, 4, 16), 256, 0, stream>>>(
            WvT + i * 262144, feat16, bv + i * 512, VT16,
            512, 512, 512, 4096, 1, 0, 0, 2097152, 0, 2097152, 0, 1.f);
        // q = x @ Wq + bq  (1024 x 512)
        gemm_bt_k<128, 128, true, false, false, true><<<dim3(4, 8, 1), 256, 0, stream>>>(
            x16, WqT + i * 262144, bq + i * 512, q16,
            512, 512, 512, 512, 1, 0, 0, 0, 0, 0, 0, 1.f);
        // S[b,h] = SCALE * q_h @ K_h^T   (batch 128: M=64,N=4096,K=64)
        gemm_bt_k<64, 128, true, false, false, false><<<dim3(32, 1, 128), 256, 0, stream>>>(
            q16, K16, nullptr, S16,
            64, 512, 512, 4096, 8, 32768, 64, 2097152, 64, 2097152, 262144, 0.125f);
        // softmax + gate -> P (reuses K16), head-avg scores -> attns
        softmax_gate_k<<<1024, 256, 0, stream>>>(
            S16, affb + i * 65536, P16, attns_base + (size_t)i * 4194304);
        // o[b,h] = P @ V, split-K 8: z = split*128 + bh  (partials over S16)
        gemm_bt_k<64, 64, false, false, false, false><<<dim3(1, 1, 1024), 256, 0, stream>>>(
            P16, VT16, nullptr, part,
            512, 4096, 4096, 64, 128, 512, 262144, 512, 262144, 524288, 4096, 1.f);
        pv_reduce_k<<<512, 256, 0, stream>>>(part, o16);
        // o @ Wo + bo -> fp32
        gemm_bt_k<128, 128, false, false, false, true><<<dim3(4, 8, 1), 256, 0, stream>>>(
            o16, WoT + i * 262144, bo + i * 512, oproj,
            512, 512, 512, 512, 1, 0, 0, 0, 0, 0, 0, 1.f);
        // x = LN(x + oproj; g2, beta2)
        ln_k<false><<<1024, 256, 0, stream>>>(xb, oproj, g2 + i * 512, be2 + i * 512, x16, nullptr);
        // h1 = relu(x @ W1 + b1) -> bf16 (1024 x 2048)
        gemm_bt_k<128, 128, true, true, false, true><<<dim3(16, 8, 1), 256, 0, stream>>>(
            x16, W1T + (size_t)i * 1048576, b1 + i * 2048, h116,
            512, 512, 512, 2048, 1, 0, 0, 0, 0, 0, 0, 1.f);
        // ff = h1 @ W2 + b2 -> fp32
        gemm_bt_k<128, 128, false, false, false, true><<<dim3(4, 8, 1), 256, 0, stream>>>(
            h116, W2T + (size_t)i * 1048576, b2 + i * 512, ffb,
            2048, 2048, 2048, 512, 1, 0, 0, 0, 0, 0, 0, 1.f);
        // x = LN(x + ff; g3, beta3), write outs[i]
        ln_k<true><<<1024, 256, 0, stream>>>(xb, ffb, g3 + i * 512, be3 + i * 512, x16,
                                             outs_base + (size_t)i * 524288);
    }
}

// Round 3
// 825.112 us; speedup vs baseline: 1.4438x; 1.2526x over previous
//
#include <hip/hip_runtime.h>

// SegDecoder: 3-layer cross-attention decoder on MI355X (gfx950).
// B=16, Nq=64, Nk=4096, C=512, H=8, hd=64, FF=2048, L=3.
// R3: BK=64 staging (halved barriers), aff folded into V, softmax fused into
// PV (P never materialized), small-GEMM tiling/split-K.

typedef unsigned short u16;
typedef __attribute__((ext_vector_type(8))) short short8;
typedef __attribute__((ext_vector_type(4))) short short4v;
typedef __attribute__((ext_vector_type(4))) float f32x4;

__device__ __forceinline__ float b2f(u16 u) {
    union { unsigned int i; float f; } v; v.i = ((unsigned int)u) << 16; return v.f;
}
__device__ __forceinline__ u16 f2b(float f) {  // round-to-nearest-even
    unsigned int x = __float_as_uint(f);
    x += 0x7fffu + ((x >> 16) & 1u);
    return (u16)(x >> 16);
}

__device__ __forceinline__ float waveSum(float v) {
#pragma unroll
    for (int o = 32; o > 0; o >>= 1) v += __shfl_xor(v, o);
    return v;
}
__device__ __forceinline__ float waveMax(float v) {
#pragma unroll
    for (int o = 32; o > 0; o >>= 1) v = fmaxf(v, __shfl_xor(v, o));
    return v;
}

// async global->LDS, 16B per lane. LDS dest is wave-uniform base + lane*16.
__device__ __forceinline__ void gl_lds16(const void* g, void* l) {
    __builtin_amdgcn_global_load_lds(
        (__attribute__((address_space(1))) void*)g,
        (__attribute__((address_space(3))) void*)l, 16, 0, 0);
}

// ---------------------------------------------------------------------------
// Generic batched GEMM:  C = alpha * A(M,K) @ Bt(N,K)^T [+ bias][*affc][relu]
// BK=64: LDS rows of 64 bf16 (128B = 8 x 16B units), unit swizzle u^(row&7).
// Staged via global_load_lds (linear LDS dest, pre-swizzled global source).
// SMAX: A holds bf16 scores s; fragment transform p=exp(s-m)*inv, stats per
// row from stats[zr*64 + row]. AFFC: epilogue *= affc[zq*4096 + col].
// ---------------------------------------------------------------------------
template<int TM, int TN, bool OUT_BF16, bool RELU, bool BIAS_ROW, bool HAS_BIAS,
         bool AFFC, bool SMAX>
__global__ __launch_bounds__(256) void gemm_bt_k(
    const u16* __restrict__ A, const u16* __restrict__ Bt,
    const float* __restrict__ bias, void* __restrict__ Cout,
    int K, int lda, int ldb, int ldc,
    int bdiv, long sA1, long sA2, long sB1, long sB2, long sC1, long sC2,
    float alpha, const float* __restrict__ affc, const float2* __restrict__ stats)
{
    __shared__ u16 As[TM][64];
    __shared__ u16 Bs[TN][64];
    const int t = threadIdx.x;
    const int lane = t & 63;
    const int wave = t >> 6;
    const int z = blockIdx.z;
    const int zq = z / bdiv, zr = z % bdiv;
    A  += (long)zq * sA1 + (long)zr * sA2;
    Bt += (long)zq * sB1 + (long)zr * sB2;
    const long cbase = (long)zq * sC1 + (long)zr * sC2;
    const int n0 = blockIdx.x * TN;
    const int m0 = blockIdx.y * TM;
    constexpr int FM = TM / 32, FN = TN / 32;
    const int wr = wave >> 1, wc = wave & 1;
    const int rl = lane & 15, uq = lane >> 4;

    float2 st[FM];
    if constexpr (SMAX) {
#pragma unroll
        for (int i = 0; i < FM; ++i)
            st[i] = stats[zr * 64 + m0 + wr * (TM / 2) + i * 16 + rl];
    }

    f32x4 acc[FM][FN];
#pragma unroll
    for (int i = 0; i < FM; ++i)
#pragma unroll
        for (int j = 0; j < FN; ++j) acc[i][j] = (f32x4){0.f, 0.f, 0.f, 0.f};

    // staging: one issue = 8 rows x 128B = 1KB; srow in [0,8), up = 16B unit
    const int srow = lane >> 3;
    const int up   = lane & 7;

    for (int k0 = 0; k0 < K; k0 += 64) {
        __syncthreads();
#pragma unroll
        for (int r = 0; r < TM / 32; ++r) {
            const int br = (wave * (TM / 32) + r) * 8;
            const int row = br + srow;
            const int ul = up ^ (row & 7);
            gl_lds16(A + (long)(m0 + row) * lda + k0 + ul * 8, &As[br][0]);
        }
#pragma unroll
        for (int r = 0; r < TN / 32; ++r) {
            const int br = (wave * (TN / 32) + r) * 8;
            const int row = br + srow;
            const int ul = up ^ (row & 7);
            gl_lds16(Bt + (long)(n0 + row) * ldb + k0 + ul * 8, &Bs[br][0]);
        }
        __syncthreads();   // drains vmcnt (global_load_lds)

#pragma unroll
        for (int kc = 0; kc < 2; ++kc) {
            short8 af[FM], bf[FN];
#pragma unroll
            for (int i = 0; i < FM; ++i) {
                const int R = wr * (TM / 2) + i * 16 + rl;
                af[i] = *(const short8*)(&As[R][((kc * 4 + uq) ^ (R & 7)) * 8]);
                if constexpr (SMAX) {
#pragma unroll
                    for (int e = 0; e < 8; ++e)
                        af[i][e] = (short)f2b(
                            __expf(b2f((u16)af[i][e]) - st[i].x) * st[i].y);
                }
            }
#pragma unroll
            for (int j = 0; j < FN; ++j) {
                const int R = wc * (TN / 2) + j * 16 + rl;
                bf[j] = *(const short8*)(&Bs[R][((kc * 4 + uq) ^ (R & 7)) * 8]);
            }
#pragma unroll
            for (int i = 0; i < FM; ++i)
#pragma unroll
                for (int j = 0; j < FN; ++j)
                    acc[i][j] = __builtin_amdgcn_mfma_f32_16x16x32_bf16(
                        af[i], bf[j], acc[i][j], 0, 0, 0);
        }
    }

    const int r0 = (lane >> 4) * 4;
    const int c0 = lane & 15;
#pragma unroll
    for (int i = 0; i < FM; ++i) {
#pragma unroll
        for (int j = 0; j < FN; ++j) {
#pragma unroll
            for (int r = 0; r < 4; ++r) {
                const int row = m0 + wr * (TM / 2) + i * 16 + r0 + r;
                const int col = n0 + wc * (TN / 2) + j * 16 + c0;
                float v = acc[i][j][r] * alpha;
                if constexpr (HAS_BIAS) {
                    if constexpr (BIAS_ROW) v += bias[row]; else v += bias[col];
                }
                if constexpr (AFFC) v *= affc[(long)zq * 4096 + col];
                if constexpr (RELU) v = fmaxf(v, 0.f);
                const long idx = cbase + (long)row * ldc + col;
                if constexpr (OUT_BF16) ((u16*)Cout)[idx] = f2b(v);
                else                    ((float*)Cout)[idx] = v;
            }
        }
    }
}

// ---------------------------------------------------------------------------
// softmax stats (m, 1/sum) per (b,h,q) + head-averaged score output.
// block = (b,q); S layout (B,H,64,4096) bf16; attns (B,64,4096) fp32.
// ---------------------------------------------------------------------------
__global__ __launch_bounds__(256) void smstats_k(
    const u16* __restrict__ S, float2* __restrict__ stats,
    float* __restrict__ attns)
{
    const int bq = blockIdx.x;
    const int b = bq >> 6, q = bq & 63;
    const int t = threadIdx.x;
    const int w = t >> 6, lane = t & 63;
    __shared__ float red[4];
    const int kb = t * 16;

    float attnacc[16];
#pragma unroll
    for (int j = 0; j < 16; ++j) attnacc[j] = 0.f;

    for (int h = 0; h < 8; ++h) {
        const long roff = (((long)(b * 8 + h)) * 64 + q) * 4096;
        const u16* Srow = S + roff;
        float v[16];
        short8 s0 = *(const short8*)(Srow + kb);
        short8 s1 = *(const short8*)(Srow + kb + 8);
#pragma unroll
        for (int j = 0; j < 8; ++j) { v[j] = b2f((u16)s0[j]); v[8 + j] = b2f((u16)s1[j]); }

        float m = -3.0e38f;
#pragma unroll
        for (int j = 0; j < 16; ++j) m = fmaxf(m, v[j]);
        m = waveMax(m);
        __syncthreads();
        if (lane == 0) red[w] = m;
        __syncthreads();
        m = fmaxf(fmaxf(red[0], red[1]), fmaxf(red[2], red[3]));

        float s = 0.f;
#pragma unroll
        for (int j = 0; j < 16; ++j) s += __expf(v[j] - m);
        s = waveSum(s);
        __syncthreads();
        if (lane == 0) red[w] = s;
        __syncthreads();
        s = red[0] + red[1] + red[2] + red[3];

        if (t == 0) stats[(b * 8 + h) * 64 + q] = make_float2(m, 1.f / s);
#pragma unroll
        for (int j = 0; j < 16; ++j) attnacc[j] += v[j];
    }
    float* arow = attns + (long)bq * 4096;
#pragma unroll
    for (int j = 0; j < 16; ++j) arow[kb + j] = attnacc[j] * 0.125f;  // /H
}

// ---------------------------------------------------------------------------
// split-K PV reduce: part (8,128,64,64) fp32 -> o16 (16,64,512) bf16
// ---------------------------------------------------------------------------
__global__ __launch_bounds__(256) void pv_reduce_k(
    const float* __restrict__ part, u16* __restrict__ o16)
{
    const int i = blockIdx.x * 256 + threadIdx.x;   // 131072 threads x 4 elems
    const int d4 = i & 15;
    const int q  = (i >> 4) & 63;
    const int bh = i >> 10;                          // 0..127
    const float* p = part + (long)bh * 4096 + q * 64 + d4 * 4;
    float4 s = {0.f, 0.f, 0.f, 0.f};
#pragma unroll
    for (int sp = 0; sp < 8; ++sp) {
        const float4 v = *(const float4*)(p + (long)sp * 524288);
        s.x += v.x; s.y += v.y; s.z += v.z; s.w += v.w;
    }
    const int b = bh >> 3, h = bh & 7;
    u16* o = o16 + (long)b * 32768 + q * 512 + h * 64 + d4 * 4;
    short4v r;
    r[0] = (short)f2b(s.x); r[1] = (short)f2b(s.y);
    r[2] = (short)f2b(s.z); r[3] = (short)f2b(s.w);
    *(short4v*)o = r;
}

// split-K FF2 reduce + bias: part (4,1024,512) fp32 -> out (1024,512) fp32
__global__ __launch_bounds__(256) void ffred_k(
    const float* __restrict__ part, const float* __restrict__ bias,
    float* __restrict__ out)
{
    const int i = (blockIdx.x * 256 + threadIdx.x) * 4;  // grid 512
    const int c = i & 511;
    float4 s = *(const float4*)(part + i);
#pragma unroll
    for (int sp = 1; sp < 4; ++sp) {
        const float4 v = *(const float4*)(part + (long)sp * 524288 + i);
        s.x += v.x; s.y += v.y; s.z += v.z; s.w += v.w;
    }
    s.x += bias[c]; s.y += bias[c + 1]; s.z += bias[c + 2]; s.w += bias[c + 3];
    *(float4*)(out + i) = s;
}

// ---------------------------------------------------------------------------
// u[l][b][c'] = sum_c Wk[l][c'][c] * extra[b][c]   (for the aff gate)
// ---------------------------------------------------------------------------
__global__ __launch_bounds__(256) void umat_k(
    const float* __restrict__ Wk, const float* __restrict__ extra,
    float* __restrict__ u)
{
    __shared__ float ex[16][512];
    const int l = blockIdx.x;
    const int t = threadIdx.x;
    for (int i = t; i < 16 * 512 / 4; i += 256)
        ((float4*)&ex[0][0])[i] = ((const float4*)extra)[i];
    __syncthreads();
    const int lane = t & 63, wave = t >> 6;
    const int row = blockIdx.y * 4 + wave;          // c' in [0,512)
    const float* wrow = Wk + ((size_t)l * 512 + row) * 512 + lane * 8;
    float w[8];
#pragma unroll
    for (int j = 0; j < 8; ++j) w[j] = wrow[j];
    float s[16];
#pragma unroll
    for (int b = 0; b < 16; ++b) {
        float x = 0.f;
#pragma unroll
        for (int j = 0; j < 8; ++j) x += w[j] * ex[b][lane * 8 + j];
        s[b] = waveSum(x);
    }
    if (lane < 16) u[((size_t)l * 16 + lane) * 512 + row] = s[lane];
}

// cb[l*16+b] = dot(extra[b], bk[l])
__global__ __launch_bounds__(256) void cbk_k(
    const float* __restrict__ bk, const float* __restrict__ extra,
    float* __restrict__ cb)
{
    const int gw = blockIdx.x * 4 + (threadIdx.x >> 6);  // 48 waves
    const int lane = threadIdx.x & 63;
    const int l = gw >> 4, b = gw & 15;
    float s = 0.f;
#pragma unroll
    for (int j = 0; j < 8; ++j)
        s += extra[b * 512 + lane * 8 + j] * bk[l * 512 + lane * 8 + j];
    s = waveSum(s);
    if (lane == 0) cb[gw] = s;
}

// ---------------------------------------------------------------------------
// feat fp32 -> bf16, fused with aff for all 3 layers:
// aff[l][b][k] = sigmoid(SCALE/H * (feat[b,k,:]·u[l][b] + cb[l][b]))
// ---------------------------------------------------------------------------
__global__ __launch_bounds__(256) void cvt16_aff_k(
    const float* __restrict__ feat, u16* __restrict__ dst,
    const float* __restrict__ u, const float* __restrict__ cb,
    float* __restrict__ affb, float* __restrict__ affs_out)
{
    const int t = blockIdx.x * 256 + threadIdx.x;
    const long i = (long)t * 8;
    const int lane = threadIdx.x & 63;
    const int r = t >> 6;           // row (b*4096 + k)
    const int b = r >> 12;
    const float4 a0 = *(const float4*)(feat + i);
    const float4 a1 = *(const float4*)(feat + i + 4);
    short8 o;
    o[0] = (short)f2b(a0.x); o[1] = (short)f2b(a0.y);
    o[2] = (short)f2b(a0.z); o[3] = (short)f2b(a0.w);
    o[4] = (short)f2b(a1.x); o[5] = (short)f2b(a1.y);
    o[6] = (short)f2b(a1.z); o[7] = (short)f2b(a1.w);
    *(short8*)(dst + i) = o;
    const float f[8] = {a0.x, a0.y, a0.z, a0.w, a1.x, a1.y, a1.z, a1.w};
#pragma unroll
    for (int l = 0; l < 3; ++l) {
        const float* ur = u + ((size_t)l * 16 + b) * 512 + lane * 8;
        float s = 0.f;
#pragma unroll
        for (int j = 0; j < 8; ++j) s += f[j] * ur[j];
        s = waveSum(s);
        if (lane == 0) {
            const float av = 1.f / (1.f + __expf(-0.015625f * (s + cb[l * 16 + b])));
            affb[l * 65536 + r] = av;
            affs_out[l * 65536 + r] = av;
        }
    }
}

// ---------------------------------------------------------------------------
// x = LN(x + add; g, beta); updates x (fp32) and x16 (bf16); optional out copy.
// ---------------------------------------------------------------------------
template<bool WRITE_OUT>
__global__ __launch_bounds__(256) void ln_k(
    float* __restrict__ x, const float* __restrict__ add,
    const float* __restrict__ g, const float* __restrict__ be,
    u16* __restrict__ x16, float* __restrict__ outp)
{
    const int r = blockIdx.x, t = threadIdx.x;
    const int w = t >> 6, lane = t & 63;
    __shared__ float red[4];
    float* xr = x + (long)r * 512;
    const float* ar = add + (long)r * 512;
    const float v0 = xr[2 * t]     + ar[2 * t];
    const float v1 = xr[2 * t + 1] + ar[2 * t + 1];
    float s = waveSum(v0 + v1);
    if (lane == 0) red[w] = s;
    __syncthreads();
    s = red[0] + red[1] + red[2] + red[3];
    const float mu = s * (1.f / 512.f);
    const float d0 = v0 - mu, d1 = v1 - mu;
    __syncthreads();
    float vs = waveSum(d0 * d0 + d1 * d1);
    if (lane == 0) red[w] = vs;
    __syncthreads();
    vs = red[0] + red[1] + red[2] + red[3];
    const float rs = rsqrtf(vs * (1.f / 512.f) + 1e-5f);
    const float o0 = g[2 * t]     * d0 * rs + be[2 * t];
    const float o1 = g[2 * t + 1] * d1 * rs + be[2 * t + 1];
    xr[2 * t] = o0; xr[2 * t + 1] = o1;
    x16[(long)r * 512 + 2 * t]     = f2b(o0);
    x16[(long)r * 512 + 2 * t + 1] = f2b(o1);
    if constexpr (WRITE_OUT) {
        outp[(long)r * 512 + 2 * t]     = o0;
        outp[(long)r * 512 + 2 * t + 1] = o1;
    }
}

// x = copy(queries) fp32 + bf16
__global__ __launch_bounds__(256) void initx_k(
    const float* __restrict__ src, float* __restrict__ x, u16* __restrict__ x16)
{
    const long i = ((long)blockIdx.x * 256 + threadIdx.x) * 8;
    const float4 a = *(const float4*)(src + i);
    const float4 b = *(const float4*)(src + i + 4);
    *(float4*)(x + i) = a;
    *(float4*)(x + i + 4) = b;
    short8 r;
    r[0] = (short)f2b(a.x); r[1] = (short)f2b(a.y); r[2] = (short)f2b(a.z); r[3] = (short)f2b(a.w);
    r[4] = (short)f2b(b.x); r[5] = (short)f2b(b.y); r[6] = (short)f2b(b.z); r[7] = (short)f2b(b.w);
    *(short8*)(x16 + i) = r;
}

// W (K,N) fp32 -> WT (N,K) bf16, batched over blockIdx.z
__global__ __launch_bounds__(256) void transpose_w_k(
    const float* __restrict__ W, u16* __restrict__ WT, int K, int N)
{
    __shared__ float tile[32][33];
    const int z = blockIdx.z;
    W  += (size_t)z * K * N;
    WT += (size_t)z * K * N;
    const int n0 = blockIdx.x * 32, k0 = blockIdx.y * 32;
    const int tx = threadIdx.x & 31, ty = threadIdx.x >> 5;
#pragma unroll
    for (int j = 0; j < 32; j += 8)
        tile[ty + j][tx] = W[(size_t)(k0 + ty + j) * N + n0 + tx];
    __syncthreads();
#pragma unroll
    for (int j = 0; j < 32; j += 8)
        WT[(size_t)(n0 + ty + j) * K + k0 + tx] = f2b(tile[tx][ty + j]);
}

// ---------------------------------------------------------------------------
extern "C" void kernel_launch(void* const* d_in, const int* in_sizes, int n_in,
                              void* d_out, int out_size, void* d_ws, size_t ws_size,
                              hipStream_t stream)
{
    (void)in_sizes; (void)n_in; (void)out_size; (void)ws_size;
    const float* queries = (const float*)d_in[0];
    const float* feat    = (const float*)d_in[1];
    const float* extra   = (const float*)d_in[2];
    const float* Wq = (const float*)d_in[3];  const float* bq = (const float*)d_in[4];
    const float* Wk = (const float*)d_in[5];  const float* bk = (const float*)d_in[6];
    const float* Wv = (const float*)d_in[7];  const float* bv = (const float*)d_in[8];
    const float* Wo = (const float*)d_in[9];  const float* bo = (const float*)d_in[10];
    const float* W1 = (const float*)d_in[11]; const float* b1 = (const float*)d_in[12];
    const float* W2 = (const float*)d_in[13]; const float* b2 = (const float*)d_in[14];
    const float* g2 = (const float*)d_in[15]; const float* be2 = (const float*)d_in[16];
    const float* g3 = (const float*)d_in[17]; const float* be3 = (const float*)d_in[18];

    char* wsb = (char*)d_ws;
    size_t off = 0;
    auto alloc = [&](size_t bytes) -> char* {
        char* p = wsb + off; off += (bytes + 255) & ~(size_t)255; return p;
    };
    u16*  feat16 = (u16*)alloc(33554432ull * 2);   // (B*Nk, C) bf16
    u16*  WqT = (u16*)alloc(786432ull * 2);        // (L,512,512) transposed
    u16*  WkT = (u16*)alloc(786432ull * 2);
    u16*  WvT = (u16*)alloc(786432ull * 2);
    u16*  WoT = (u16*)alloc(786432ull * 2);
    u16*  W1T = (u16*)alloc(3145728ull * 2);       // (L,2048,512)
    u16*  W2T = (u16*)alloc(3145728ull * 2);       // (L,512,2048)
    u16*  K16 = (u16*)alloc(33554432ull * 2);      // (B,Nk,C); later PV partials
    u16*  VT16 = (u16*)alloc(33554432ull * 2);     // (B,C,Nk) aff-gated; later FF2 partials
    u16*  q16 = (u16*)alloc(524288ull * 2);        // (B*Nq, C)
    u16*  S16 = (u16*)alloc(33554432ull * 2);      // (B,H,64,4096) scores*SCALE
    float* affb  = (float*)alloc(196608ull * 4);   // (L,B,Nk)
    u16*  o16 = (u16*)alloc(524288ull * 2);        // attention out (B,Nq,C)
    float* oproj = (float*)alloc(524288ull * 4);
    float* xb    = (float*)alloc(524288ull * 4);
    u16*  x16 = (u16*)alloc(524288ull * 2);
    u16*  h116 = (u16*)alloc(2097152ull * 2);      // (B*Nq, 2048)
    float* ffb   = (float*)alloc(524288ull * 4);
    float* uvec  = (float*)alloc(24576ull * 4);    // (L,16,512)
    float* cb    = (float*)alloc(48ull * 4);
    float2* stats = (float2*)alloc(8192ull * 8);   // (B*H*64) {m, 1/sum}
    float* partPV = (float*)K16;                   // alias: K dead after S-GEMM
    float* part2  = (float*)VT16;                  // alias: VT dead after PV

    float* out_f = (float*)d_out;
    float* outs_base  = out_f;                     // (3,16,64,512)
    float* attns_base = out_f + 1572864;           // (3,16,64,4096)
    float* affs_base  = out_f + 14155776;          // (3,16,1,1,4096)

    // prep (layer-independent)
    umat_k<<<dim3(3, 128), 256, 0, stream>>>(Wk, extra, uvec);
    cbk_k<<<12, 256, 0, stream>>>(bk, extra, cb);
    cvt16_aff_k<<<16384, 256, 0, stream>>>(feat, feat16, uvec, cb, affb, affs_base);
    initx_k<<<256, 256, 0, stream>>>(queries, xb, x16);
    transpose_w_k<<<dim3(16, 16, 3), 256, 0, stream>>>(Wq, WqT, 512, 512);
    transpose_w_k<<<dim3(16, 16, 3), 256, 0, stream>>>(Wk, WkT, 512, 512);
    transpose_w_k<<<dim3(16, 16, 3), 256, 0, stream>>>(Wv, WvT, 512, 512);
    transpose_w_k<<<dim3(16, 16, 3), 256, 0, stream>>>(Wo, WoT, 512, 512);
    transpose_w_k<<<dim3(64, 16, 3), 256, 0, stream>>>(W1, W1T, 512, 2048);
    transpose_w_k<<<dim3(16, 64, 3), 256, 0, stream>>>(W2, W2T, 2048, 512);

    for (int i = 0; i < 3; ++i) {
        // K = feat @ Wk + bk   (M=65536, N=512, K=512) -> bf16 (B,Nk,C)
        gemm_bt_k<128, 128, true, false, false, true, false, false>
            <<<dim3(4, 512, 1), 256, 0, stream>>>(
            feat16, WkT + i * 262144, bk + i * 512, K16,
            512, 512, 512, 512, 1, 0, 0, 0, 0, 0, 0, 1.f, nullptr, nullptr);
        // VT'[b] = aff ⊙ ((feat[b] @ Wv)^T + bv)  -> (B,C,Nk)
        gemm_bt_k<128, 128, true, false, true, true, true, false>
            <<<dim3(32, 4, 16), 256, 0, stream>>>(
            WvT + i * 262144, feat16, bv + i * 512, VT16,
            512, 512, 512, 4096, 1, 0, 0, 2097152, 0, 2097152, 0, 1.f,
            affb + i * 65536, nullptr);
        // q = x @ Wq + bq  (1024 x 512)
        gemm_bt_k<64, 64, true, false, false, true, false, false>
            <<<dim3(8, 16, 1), 256, 0, stream>>>(
            x16, WqT + i * 262144, bq + i * 512, q16,
            512, 512, 512, 512, 1, 0, 0, 0, 0, 0, 0, 1.f, nullptr, nullptr);
        // S[b,h] = SCALE * q_h @ K_h^T   (batch 128: M=64,N=4096,K=64)
        gemm_bt_k<64, 128, true, false, false, false, false, false>
            <<<dim3(32, 1, 128), 256, 0, stream>>>(
            q16, K16, nullptr, S16,
            64, 512, 512, 4096, 8, 32768, 64, 2097152, 64, 2097152, 262144,
            0.125f, nullptr, nullptr);
        // softmax stats + attns
        smstats_k<<<1024, 256, 0, stream>>>(
            S16, stats, attns_base + (size_t)i * 4194304);
        // o[b,h] = softmax(S) @ V', split-K 8, softmax fused at fragment load
        gemm_bt_k<64, 64, false, false, false, false, false, true>
            <<<dim3(1, 1, 1024), 256, 0, stream>>>(
            S16, VT16, nullptr, partPV,
            512, 4096, 4096, 64, 128, 512, 262144, 512, 262144, 524288, 4096,
            1.f, nullptr, stats);
        pv_reduce_k<<<512, 256, 0, stream>>>(partPV, o16);
        // o @ Wo + bo -> fp32
        gemm_bt_k<64, 64, false, false, false, true, false, false>
            <<<dim3(8, 16, 1), 256, 0, stream>>>(
            o16, WoT + i * 262144, bo + i * 512, oproj,
            512, 512, 512, 512, 1, 0, 0, 0, 0, 0, 0, 1.f, nullptr, nullptr);
        // x = LN(x + oproj; g2, beta2)
        ln_k<false><<<1024, 256, 0, stream>>>(xb, oproj, g2 + i * 512, be2 + i * 512, x16, nullptr);
        // h1 = relu(x @ W1 + b1) -> bf16 (1024 x 2048)
        gemm_bt_k<64, 128, true, true, false, true, false, false>
            <<<dim3(16, 16, 1), 256, 0, stream>>>(
            x16, W1T + (size_t)i * 1048576, b1 + i * 2048, h116,
            512, 512, 512, 2048, 1, 0, 0, 0, 0, 0, 0, 1.f, nullptr, nullptr);
        // ff partials = h1 @ W2 (split-K 4) -> fp32 (4,1024,512)
        gemm_bt_k<64, 64, false, false, false, false, false, false>
            <<<dim3(8, 16, 4), 256, 0, stream>>>(
            h116, W2T + (size_t)i * 1048576, nullptr, part2,
            512, 2048, 2048, 512, 1, 512, 0, 512, 0, 524288, 0,
            1.f, nullptr, nullptr);
        ffred_k<<<512, 256, 0, stream>>>(part2, b2 + i * 512, ffb);
        // x = LN(x + ff; g3, beta3), write outs[i]
        ln_k<true><<<1024, 256, 0, stream>>>(xb, ffb, g3 + i * 512, be3 + i * 512, x16,
                                             outs_base + (size_t)i * 524288);
    }
}